// Round 1
// baseline (472.270 us; speedup 1.0000x reference)
//
#include <hip/hip_runtime.h>
#include <hip/hip_bf16.h>
#include <cstdint>

// ---------------------------------------------------------------------------
// DGNN pipeline, fp32, CSR-based aggregation (no scatter atomics on features).
// Biases gcn_b / dcn_b cancel inside the following batchnorms (per-channel
// additive shift -> mean shifts identically, variance unchanged) and are
// skipped.
// ---------------------------------------------------------------------------

// Detect whether edge_index arrived as int64 (high int32 words all zero for
// values < 2^31) or int32 (odd int32 positions are random node ids).
__global__ void detect_kernel(const int* __restrict__ ei32, int* __restrict__ flag) {
    int t = threadIdx.x;
    int v = ei32[2 * t + 1];
    if (v != 0) atomicOr(flag, 1);   // nonzero high-word sample => int32 layout
}

__global__ void convert_kernel(const void* __restrict__ ei, int E,
                               const int* __restrict__ flag,
                               int* __restrict__ rowi, int* __restrict__ coli,
                               int* __restrict__ count) {
    int f = *flag;
    int stride = gridDim.x * blockDim.x;
    for (int e = blockIdx.x * blockDim.x + threadIdx.x; e < E; e += stride) {
        int r, c;
        if (f) {
            r = ((const int*)ei)[e];
            c = ((const int*)ei)[E + e];
        } else {
            r = (int)((const long long*)ei)[e];
            c = (int)((const long long*)ei)[E + e];
        }
        rowi[e] = r;
        coli[e] = c;
        atomicAdd(&count[c], 1);
    }
}

// Single-block exclusive prefix sum over counts; also emits dinv = rsqrt(deg+1).
__global__ void scan_kernel(const int* __restrict__ count, int* __restrict__ base,
                            float* __restrict__ dinv, int n) {
    __shared__ int sm[1024];
    __shared__ int s_run;
    int t = threadIdx.x;
    if (t == 0) s_run = 0;
    __syncthreads();
    for (int start = 0; start < n; start += 1024) {
        int i = start + t;
        int v = (i < n) ? count[i] : 0;
        sm[t] = v;
        __syncthreads();
        for (int off = 1; off < 1024; off <<= 1) {
            int add = (t >= off) ? sm[t - off] : 0;
            __syncthreads();
            sm[t] += add;
            __syncthreads();
        }
        int incl = sm[t];
        int run = s_run;
        if (i < n) {
            base[i] = run + incl - v;                 // exclusive
            dinv[i] = rsqrtf((float)(v + 1));         // +1 self loop; always > 0
        }
        __syncthreads();
        if (t == 1023) s_run = run + incl;
        __syncthreads();
    }
}

__global__ void scatter_kernel(const int* __restrict__ rowi, const int* __restrict__ coli,
                               const int* __restrict__ base, int* __restrict__ cursor,
                               int* __restrict__ esrc, int E) {
    int stride = gridDim.x * blockDim.x;
    for (int e = blockIdx.x * blockDim.x + threadIdx.x; e < E; e += stride) {
        int c = coli[e];
        int pos = base[c] + atomicAdd(&cursor[c], 1);
        esrc[pos] = rowi[e];
    }
}

// Y[N][128] = X[N][128] @ W[128][128], fp32. W staged in LDS (64 KiB).
// Block: 256 threads; 8 rows per iteration; thread t -> row t/32, cols 4*(t%32)..+3.
__global__ __launch_bounds__(256) void gemm128_kernel(const float* __restrict__ X,
                                                      const float* __restrict__ W,
                                                      float* __restrict__ Y, int n) {
    __shared__ float Wl[128 * 128];
    int t = threadIdx.x;
    for (int i = t * 4; i < 128 * 128; i += 1024) {
        *(float4*)&Wl[i] = *(const float4*)&W[i];
    }
    __syncthreads();
    int rl = t >> 5;           // 0..7
    int c4 = (t & 31) * 4;     // column base
    for (int r0 = blockIdx.x * 8; r0 < n; r0 += gridDim.x * 8) {
        int r = r0 + rl;
        if (r < n) {
            float4 acc = {0.f, 0.f, 0.f, 0.f};
            const float* xr = &X[(size_t)r * 128];
            for (int k = 0; k < 128; k += 4) {
                float4 xv = *(const float4*)&xr[k];   // broadcast across 32 lanes
                float4 w0 = *(float4*)&Wl[(k + 0) * 128 + c4];
                acc.x += xv.x * w0.x; acc.y += xv.x * w0.y; acc.z += xv.x * w0.z; acc.w += xv.x * w0.w;
                float4 w1 = *(float4*)&Wl[(k + 1) * 128 + c4];
                acc.x += xv.y * w1.x; acc.y += xv.y * w1.y; acc.z += xv.y * w1.z; acc.w += xv.y * w1.w;
                float4 w2 = *(float4*)&Wl[(k + 2) * 128 + c4];
                acc.x += xv.z * w2.x; acc.y += xv.z * w2.y; acc.z += xv.z * w2.z; acc.w += xv.z * w2.w;
                float4 w3 = *(float4*)&Wl[(k + 3) * 128 + c4];
                acc.x += xv.w * w3.x; acc.y += xv.w * w3.y; acc.z += xv.w * w3.z; acc.w += xv.w * w3.w;
            }
            *(float4*)&Y[(size_t)r * 128 + c4] = acc;
        }
    }
}

// One wave per node: out[n][c] = dinv[n]*( sum_src dinv[src]*XW[src][c] + dinv[n]*XW[n][c] )
__global__ void prop_kernel(const float* __restrict__ XW, const int* __restrict__ base,
                            const int* __restrict__ count, const int* __restrict__ esrc,
                            const float* __restrict__ dinv, float* __restrict__ out, int n) {
    int wave = (int)((blockIdx.x * blockDim.x + threadIdx.x) >> 6);
    int lane = threadIdx.x & 63;
    if (wave >= n) return;
    int b = base[wave];
    int cnt = count[wave];
    float din = dinv[wave];
    const float2* xw2 = (const float2*)XW;
    float2 acc = {0.f, 0.f};
    for (int i = 0; i < cnt; i++) {
        int src = esrc[b + i];
        float w = dinv[src];
        float2 v = xw2[(size_t)src * 64 + lane];
        acc.x += w * v.x;
        acc.y += w * v.y;
    }
    float2 vs = xw2[(size_t)wave * 64 + lane];
    acc.x = din * (acc.x + din * vs.x);
    acc.y = din * (acc.y + din * vs.y);
    ((float2*)out)[(size_t)wave * 64 + lane] = acc;
}

// Per-channel sum / sumsq over rows; optional elementwise gate M <- M*H first.
__global__ void stats_kernel(float* __restrict__ M, const float* __restrict__ H,
                             float* __restrict__ sums, float* __restrict__ sumsq,
                             int n, int gate) {
    int t = threadIdx.x;
    int col = t & 127;
    int rhalf = t >> 7;  // 0..1
    float s = 0.f, s2 = 0.f;
    for (int r = blockIdx.x * 2 + rhalf; r < n; r += gridDim.x * 2) {
        size_t idx = (size_t)r * 128 + col;
        float v = M[idx];
        if (gate) { v = v * H[idx]; M[idx] = v; }
        s += v;
        s2 += v * v;
    }
    __shared__ float ls[256], ls2[256];
    ls[t] = s; ls2[t] = s2;
    __syncthreads();
    if (t < 128) {
        s = ls[t] + ls[t + 128];
        s2 = ls2[t] + ls2[t + 128];
        atomicAdd(&sums[col], s);
        atomicAdd(&sumsq[col], s2);
    }
}

__global__ void bnapply_kernel(const float* __restrict__ M, const float* __restrict__ sums,
                               const float* __restrict__ sumsq,
                               const float* __restrict__ g, const float* __restrict__ bet,
                               float* __restrict__ Hout, int n) {
    size_t total = (size_t)n * 128;
    float invn = 1.f / (float)n;
    for (size_t idx = (size_t)blockIdx.x * blockDim.x + threadIdx.x; idx < total;
         idx += (size_t)gridDim.x * blockDim.x) {
        int col = (int)(idx & 127);
        float mu = sums[col] * invn;
        float var = sumsq[col] * invn - mu * mu;
        float a = g[col] * rsqrtf(var + 1e-5f);
        float b = bet[col] - mu * a;
        Hout[idx] = M[idx] * a + b;
    }
}

// result[n] = dot(h[n], ow[0:128]) + dot(BN3(gated[n]), ow[128:256]) + ob
__global__ void final_kernel(const float* __restrict__ H, const float* __restrict__ G,
                             const float* __restrict__ sums3, const float* __restrict__ sumsq3,
                             const float* __restrict__ g3, const float* __restrict__ b3,
                             const float* __restrict__ ow, const float* __restrict__ ob,
                             float* __restrict__ out, int n) {
    int wave = (int)((blockIdx.x * blockDim.x + threadIdx.x) >> 6);
    int lane = threadIdx.x & 63;
    if (wave >= n) return;
    int c0 = 2 * lane, c1 = c0 + 1;
    float invn = 1.f / (float)n;
    float2 h2 = ((const float2*)H)[(size_t)wave * 64 + lane];
    float2 g2 = ((const float2*)G)[(size_t)wave * 64 + lane];
    float mu0 = sums3[c0] * invn;
    float var0 = sumsq3[c0] * invn - mu0 * mu0;
    float a0 = g3[c0] * rsqrtf(var0 + 1e-5f);
    float bb0 = b3[c0] - mu0 * a0;
    float mu1 = sums3[c1] * invn;
    float var1 = sumsq3[c1] * invn - mu1 * mu1;
    float a1 = g3[c1] * rsqrtf(var1 + 1e-5f);
    float bb1 = b3[c1] - mu1 * a1;
    float o0 = g2.x * a0 + bb0;
    float o1 = g2.y * a1 + bb1;
    float partial = h2.x * ow[c0] + h2.y * ow[c1] + o0 * ow[128 + c0] + o1 * ow[128 + c1];
    #pragma unroll
    for (int off = 32; off > 0; off >>= 1) partial += __shfl_down(partial, off);
    if (lane == 0) out[wave] = partial + ob[0];
}

extern "C" void kernel_launch(void* const* d_in, const int* in_sizes, int n_in,
                              void* d_out, int out_size, void* d_ws, size_t ws_size,
                              hipStream_t stream) {
    const float* x     = (const float*)d_in[0];
    const void*  ei    = d_in[1];
    const float* gcn_w = (const float*)d_in[2];
    const float* bn1_g = (const float*)d_in[4];
    const float* bn1_b = (const float*)d_in[5];
    const float* dcn_w = (const float*)d_in[6];
    const float* bn3_g = (const float*)d_in[8];
    const float* bn3_b = (const float*)d_in[9];
    const float* out_w = (const float*)d_in[10];
    const float* out_b = (const float*)d_in[11];
    float* out = (float*)d_out;

    int N = in_sizes[0] / 128;
    int E = in_sizes[1] / 2;
    size_t N128 = (size_t)N * 128;

    float* A     = (float*)d_ws;            // xw / hw           [N*128]
    float* B     = A + N128;                // agg (reused)      [N*128]
    float* H     = B + N128;                // h                 [N*128]
    int*   rowi  = (int*)(H + N128);        // [E]
    int*   coli  = rowi + E;                // [E]
    int*   esrc  = coli + E;                // [E]
    float* dinv  = (float*)(esrc + E);      // [N]
    int*   base  = (int*)(dinv + N);        // [N]
    // ---- zeroed region starts here ----
    int*   count  = base + N;               // [N]
    int*   cursor = count + N;              // [N]
    float* sums1  = (float*)(cursor + N);   // [128]
    float* sumsq1 = sums1 + 128;            // [128]
    float* sums3  = sumsq1 + 128;           // [128]
    float* sumsq3 = sums3 + 128;            // [128]
    int*   flag   = (int*)(sumsq3 + 128);   // [1]

    size_t zero_bytes = (size_t)((char*)(flag + 1) - (char*)count);
    hipMemsetAsync(count, 0, zero_bytes, stream);

    int egrid = (E + 255) / 256;
    if (egrid > 2048) egrid = 2048;
    int pgrid = (N + 3) / 4;   // 4 waves / block, one node per wave

    detect_kernel<<<1, 1024, 0, stream>>>((const int*)ei, flag);
    convert_kernel<<<egrid, 256, 0, stream>>>(ei, E, flag, rowi, coli, count);
    scan_kernel<<<1, 1024, 0, stream>>>(count, base, dinv, N);
    scatter_kernel<<<egrid, 256, 0, stream>>>(rowi, coli, base, cursor, esrc, E);

    gemm128_kernel<<<512, 256, 0, stream>>>(x, gcn_w, A, N);
    prop_kernel<<<pgrid, 256, 0, stream>>>(A, base, count, esrc, dinv, B, N);
    stats_kernel<<<1024, 256, 0, stream>>>(B, nullptr, sums1, sumsq1, N, 0);

    int agrid = (int)((N128 + 255) / 256);
    if (agrid > 4096) agrid = 4096;
    bnapply_kernel<<<agrid, 256, 0, stream>>>(B, sums1, sumsq1, bn1_g, bn1_b, H, N);

    gemm128_kernel<<<512, 256, 0, stream>>>(H, dcn_w, A, N);
    prop_kernel<<<pgrid, 256, 0, stream>>>(A, base, count, esrc, dinv, B, N);
    stats_kernel<<<1024, 256, 0, stream>>>(B, H, sums3, sumsq3, N, 1);

    final_kernel<<<pgrid, 256, 0, stream>>>(H, B, sums3, sumsq3, bn3_g, bn3_b,
                                            out_w, out_b, out, N);
}